// Round 1
// baseline (735.060 us; speedup 1.0000x reference)
//
#include <hip/hip_runtime.h>
#include <hip/hip_bf16.h>
#include <math.h>

// ============================================================================
// Fractal-flame chaos game — bit-exact reproduction of the JAX reference RNG.
//
// ASSUMPTION LEDGER (flip one macro per round based on failure signature):
//   RNG_PARTITIONABLE=1 : jax>=0.4.36 default (threefry_partitionable=True).
//       Wrong => whole image differs => absmax ~0.3-1.5. Flip to 0.
//   OUT_BF16=0          : reference output promotes to f32 (hist is f32).
//       Wrong => absmax astronomically large (bf16-decoding f32 bits). Flip to 1.
//   COLSUM_F32_ACCUM=1  : XLA FloatNormalization accumulates bf16 reduce in f32.
//       Wrong => many CDF boundary flips => absmax ~0.1-0.5. Flip to 0.
//   Input dtype auto-detected per launch (bf16 vs f32 plausibility vote).
//   f32-input mode only: exp() via correctly-rounded double (glibc-expf-like).
// ============================================================================

#define RNG_PARTITIONABLE 1
#define OUT_BF16 0
#define COLSUM_F32_ACCUM 1

typedef unsigned int u32;
typedef unsigned short u16;

static constexpr int FN = 8;
static constexpr int HH = 1024;
static constexpr int WW = 1024;
static constexpr int NP = 65536;
static constexpr int TI = 48;
static constexpr int WARM = 8;
static constexpr int HWPIX = HH * WW;

// meta layout (float/u32 indices into meta block after hist in ws)
static constexpr int META_CUMPT = 0;    // 64 f32: cumP transposed [cur][next]
static constexpr int META_AFF   = 64;   // 48 f32
static constexpr int META_CT    = 112;  // 24 f32
static constexpr int META_BG    = 136;  // 3 f32
static constexpr int META_FLAG  = 139;  // 1 f32 (1.0 if bf16 inputs)
static constexpr int META_KEYS  = 140;  // 96 u32 (48 key pairs)
static constexpr int META_KX    = 236;  // 2 u32
static constexpr int META_K2S   = 238;  // 2 u32  (contiguous with KX)

struct U2 { u32 x, y; };

// ---------------------------------------------------------------- threefry2x32
__device__ __forceinline__ U2 tf2x32(u32 k0, u32 k1, u32 c0, u32 c1) {
  u32 ks2 = k0 ^ k1 ^ 0x1BD11BDAu;
  u32 x0 = c0 + k0, x1 = c1 + k1;
#define TF_R(r) { x0 += x1; x1 = (x1 << (r)) | (x1 >> (32 - (r))); x1 ^= x0; }
  TF_R(13) TF_R(15) TF_R(26) TF_R(6)
  x0 += k1; x1 += ks2 + 1u;
  TF_R(17) TF_R(29) TF_R(16) TF_R(24)
  x0 += ks2; x1 += k0 + 2u;
  TF_R(13) TF_R(15) TF_R(26) TF_R(6)
  x0 += k0; x1 += k1 + 3u;
  TF_R(17) TF_R(29) TF_R(16) TF_R(24)
  x0 += k1; x1 += ks2 + 4u;
  TF_R(13) TF_R(15) TF_R(26) TF_R(6)
  x0 += ks2; x1 += k0 + 5u;
#undef TF_R
  return {x0, x1};
}

// random_bits(key, 32, (n,)) element i; halfN = n/2 (original pairing only)
__device__ __forceinline__ u32 rbits(U2 key, u32 i, u32 halfN) {
#if RNG_PARTITIONABLE
  (void)halfN;
  U2 r = tf2x32(key.x, key.y, 0u, i);
  return r.x ^ r.y;
#else
  if (i < halfN) { U2 r = tf2x32(key.x, key.y, i, i + halfN); return r.x; }
  else           { U2 r = tf2x32(key.x, key.y, i - halfN, i); return r.y; }
#endif
}

__device__ __forceinline__ float unitf(u32 b) {  // jax uniform [0,1)
  return __uint_as_float((b >> 9) | 0x3F800000u) - 1.0f;
}

// ---------------------------------------------------------------- bf16 helpers
__device__ __forceinline__ float bf2f(u16 h) { return __uint_as_float(((u32)h) << 16); }
__device__ __forceinline__ float rndbf(float x) {  // f32 -> bf16 RNE -> f32
  u32 u = __float_as_uint(x);
  u32 r = (u + 0x7FFFu + ((u >> 16) & 1u)) & 0xFFFF0000u;
  return __uint_as_float(r);
}
__device__ __forceinline__ float rnd_m(float x, bool bf) { return bf ? rndbf(x) : x; }
__device__ __forceinline__ float ldf(const void* p, int i, bool bf) {
  return bf ? bf2f(((const u16*)p)[i]) : ((const float*)p)[i];
}

// correctly-rounded f32 exp via double (matches glibc scalar expf path)
__device__ __forceinline__ float exp_cr(float x) { return (float)exp((double)x); }

// XLA LogisticExpander: 1/(1+exp(-x)), per-op bf16 rounding when bf
__device__ __forceinline__ float sigchain(float x, bool bf) {
  float e = rnd_m(exp_cr(-x), bf);
  float d = rnd_m(1.0f + e, bf);
  return rnd_m(1.0f / d, bf);
}

__device__ __forceinline__ void atomAddF(float* p, float v) {
  unsafeAtomicAdd(p, v);  // hardware global_atomic_add_f32 (values are normal)
}

// ============================================================== setup kernel
__global__ __launch_bounds__(64) void setup_kernel(const void* pn, const void* affp,
                                                   const void* ctp, const void* bgp,
                                                   float* meta) {
  __shared__ int vote;
  __shared__ float sP[64];
  __shared__ u32 sroot[8];  // kx.x kx.y ks.x ks.y kl.x kl.y k2.x k2.y
  int tid = threadIdx.x;
  if (tid == 0) vote = 0;
  __syncthreads();
  // dtype vote: reinterpret prob_norm as bf16[64]; true-bf16 => ~64 plausible,
  // f32 => only odd halves (~34) plausible.
  {
    float v = fabsf(bf2f(((const u16*)pn)[tid]));
    if (v > 1e-4f && v < 16.0f) atomicAdd(&vote, 1);
  }
  __syncthreads();
  bool bf = (vote >= 50);

  // ---- root key derivations (thread 0) -------------------------------------
  if (tid == 0) {
    meta[META_FLAG] = bf ? 1.0f : 0.0f;
    u32* mu = (u32*)meta;
#if RNG_PARTITIONABLE
    U2 kx = tf2x32(0u, 42u, 0u, 0u);   // split(key(42),3)[0]
    U2 ks = tf2x32(0u, 42u, 0u, 1u);   // [1]
    U2 kl = tf2x32(0u, 42u, 0u, 2u);   // [2]
    U2 k2 = tf2x32(ks.x, ks.y, 0u, 1u);  // randint: _split(ks)[1]
#else
    U2 t0 = tf2x32(0u, 42u, 0u, 3u), t1 = tf2x32(0u, 42u, 1u, 4u), t2 = tf2x32(0u, 42u, 2u, 5u);
    U2 kx{t0.x, t1.x}, ks{t2.x, t0.y}, kl{t1.y, t2.y};
    U2 r0 = tf2x32(ks.x, ks.y, 0u, 2u), r1 = tf2x32(ks.x, ks.y, 1u, 3u);
    U2 k2{r0.y, r1.y};
#endif
    sroot[0] = kx.x; sroot[1] = kx.y; sroot[2] = ks.x; sroot[3] = ks.y;
    sroot[4] = kl.x; sroot[5] = kl.y; sroot[6] = k2.x; sroot[7] = k2.y;
    mu[META_KX] = kx.x; mu[META_KX + 1] = kx.y;
    mu[META_K2S] = k2.x; mu[META_K2S + 1] = k2.y;
  }

  // ---- parameters ----------------------------------------------------------
  // P = sigmoid(prob_norm) + 0.001 (0.001 is bf16-rounded in bf16 mode)
  float c001 = bf ? 0.00099945068359375f : 0.001f;
  sP[tid] = rnd_m(sigchain(ldf(pn, tid, bf), bf) + c001, bf);
  if (tid < 48) meta[META_AFF + tid] = ldf(affp, tid, bf);
  if (tid < 24) meta[META_CT + tid] = sigchain(ldf(ctp, tid, bf), bf);
  if (tid < 3)  meta[META_BG + tid] = sigchain(ldf(bgp, tid, bf), bf);
  __syncthreads();

  // ---- iteration keys: split(kloop, 48) ------------------------------------
  if (tid < 48) {
    U2 kl{sroot[4], sroot[5]};
    u32* mu = (u32*)meta;
#if RNG_PARTITIONABLE
    U2 kt = tf2x32(kl.x, kl.y, 0u, (u32)tid);
#else
    u32 e0 = 2u * tid, e1 = 2u * tid + 1u;
    u32 w0 = (e0 < 48u) ? tf2x32(kl.x, kl.y, e0, e0 + 48u).x : tf2x32(kl.x, kl.y, e0 - 48u, e0).y;
    u32 w1 = (e1 < 48u) ? tf2x32(kl.x, kl.y, e1, e1 + 48u).x : tf2x32(kl.x, kl.y, e1 - 48u, e1).y;
    U2 kt{w0, w1};
#endif
    mu[META_KEYS + 2 * tid]     = kt.x;
    mu[META_KEYS + 2 * tid + 1] = kt.y;
  }

  // ---- per-column: colsum, normalize, cumsum (associative_scan tree) -------
  if (tid < 8) {
    int c = tid;
    float a[8];
#if COLSUM_F32_ACCUM
    float cs = 0.0f;
    for (int r = 0; r < 8; ++r) cs += sP[r * 8 + c];
    cs = rnd_m(cs, bf);
#else
    float cs = 0.0f;
    for (int r = 0; r < 8; ++r) cs = rnd_m(cs + sP[r * 8 + c], bf);
#endif
    for (int r = 0; r < 8; ++r) a[r] = rnd_m(sP[r * 8 + c] / cs, bf);
    // jnp.cumsum lowers to associative_scan on CPU/GPU: tree, NOT sequential.
    float b0 = rnd_m(a[0] + a[1], bf), b1 = rnd_m(a[2] + a[3], bf);
    float b2 = rnd_m(a[4] + a[5], bf), b3 = rnd_m(a[6] + a[7], bf);
    float c0 = rnd_m(b0 + b1, bf), c1v = rnd_m(b2 + b3, bf);
    float d0 = rnd_m(c0 + c1v, bf);
    float s5 = rnd_m(c0 + b2, bf);
    float cum[8] = { a[0], b0, rnd_m(b0 + a[2], bf), c0,
                     rnd_m(c0 + a[4], bf), s5, rnd_m(s5 + a[6], bf), d0 };
    for (int r = 0; r < 8; ++r) meta[META_CUMPT + c * 8 + r] = cum[r];
  }
}

// ============================================================== chaos kernel
__global__ __launch_bounds__(256) void chaos_kernel(const float* __restrict__ meta,
                                                    float* __restrict__ hist) {
  __shared__ float cumPT[64];  // [cur][next]
  __shared__ float aff[48];
  __shared__ u32 keyw[96];
  __shared__ u32 rk[4];
  int tid = threadIdx.x;
  if (tid < 64) cumPT[tid] = meta[META_CUMPT + tid];
  if (tid < 48) aff[tid] = meta[META_AFF + tid];
  const u32* mu = (const u32*)meta;
  if (tid < 96) keyw[tid] = mu[META_KEYS + tid];
  if (tid < 4)  rk[tid] = mu[META_KX + tid];
  __syncthreads();

  u32 n = blockIdx.x * 256u + (u32)tid;
  U2 kx{rk[0], rk[1]}, k2{rk[2], rk[3]};
  // x = uniform(kx,(N,2),-1,1): flat elem (n,d) at 2n+d, total 131072
  float x = fmaxf(-1.0f, unitf(rbits(kx, 2u * n,      65536u)) * 2.0f - 1.0f);
  float y = fmaxf(-1.0f, unitf(rbits(kx, 2u * n + 1u, 65536u)) * 2.0f - 1.0f);
  // s = randint(ks,(N,),0,8) == lower_bits % 8 (multiplier is 0 for span=8)
  int s = (int)(rbits(k2, n, 32768u) & 7u);

  for (int t = 0; t < TI; ++t) {
    U2 kt{keyw[2 * t], keyw[2 * t + 1]};
    float u = unitf(rbits(kt, n, 32768u));
    int cnt = 0;
#pragma unroll
    for (int r = 0; r < 8; ++r) cnt += (cumPT[s * 8 + r] < u) ? 1 : 0;
    int nxt = cnt < 7 ? cnt : 7;
    const float* A = &aff[nxt * 6];
    float xn = A[0] * x + A[1] * y + A[2];
    float yn = A[3] * x + A[4] * y + A[5];
    x = xn; y = yn; s = nxt;
    if (t >= WARM) {
      float gx = (x + 1.0f) * 0.5f * 1024.0f - 0.5f;
      float gy = (y + 1.0f) * 0.5f * 1024.0f - 0.5f;
      float fx0 = floorf(gx), fy0 = floorf(gy);
      float fx = gx - fx0, fy = gy - fy0;
      int xi = (int)fx0, yi = (int)fy0;
      float ofx = 1.0f - fx, ofy = 1.0f - fy;
      float* hb = hist + (size_t)nxt * HWPIX;
      if (((u32)xi < 1024u) && ((u32)yi < 1024u))           atomAddF(hb + yi * 1024 + xi,             ofx * ofy);
      if (((u32)(xi + 1) < 1024u) && ((u32)yi < 1024u))     atomAddF(hb + yi * 1024 + (xi + 1),       fx * ofy);
      if (((u32)xi < 1024u) && ((u32)(yi + 1) < 1024u))     atomAddF(hb + (yi + 1) * 1024 + xi,       ofx * fy);
      if (((u32)(xi + 1) < 1024u) && ((u32)(yi + 1) < 1024u)) atomAddF(hb + (yi + 1) * 1024 + (xi + 1), fx * fy);
    }
  }
}

// ============================================================ compose kernel
__global__ __launch_bounds__(256) void compose_kernel(const float* __restrict__ hist,
                                                      const float* __restrict__ meta,
                                                      void* __restrict__ outv) {
  int p = blockIdx.x * 256 + threadIdx.x;
  if (p >= HWPIX) return;
  bool bf = meta[META_FLAG] != 0.0f;
  float h[8];
#pragma unroll
  for (int f = 0; f < 8; ++f) h[f] = hist[f * HWPIX + p];
  float hs = h[0];
#pragma unroll
  for (int f = 1; f < 8; ++f) hs += h[f];
  float denom = hs + 1e-5f;
  // nexp = exposure * 0.4 / kr^2 ; in bf16-scalar mode 0.4 rounds to 0.400390625
  float nexp = bf ? 0.10009765625f : 0.1f;
  float inten = log1pf(hs * nexp);
  float alpha = fminf(fmaxf(inten, 0.0f), 1.0f);
  float oma = 1.0f - alpha;
  float cn[8];
#pragma unroll
  for (int f = 0; f < 8; ++f) cn[f] = h[f] / denom;
#pragma unroll
  for (int c = 0; c < 3; ++c) {
    float rgb = 0.0f;
#pragma unroll
    for (int f = 0; f < 8; ++f) rgb += meta[META_CT + c * 8 + f] * cn[f];
    float v = fmaxf(rgb * alpha, 1e-8f);
    float img = sqrtf(v);  // pow(x, 1/gamma) with gamma=2
    float o = img + meta[META_BG + c] * oma;
#if OUT_BF16
    ((__hip_bfloat16*)outv)[c * HWPIX + p] = __float2bfloat16(o);
#else
    ((float*)outv)[c * HWPIX + p] = o;
#endif
  }
}

// ================================================================= launcher
extern "C" void kernel_launch(void* const* d_in, const int* in_sizes, int n_in,
                              void* d_out, int out_size, void* d_ws, size_t ws_size,
                              hipStream_t stream) {
  (void)in_sizes; (void)n_in; (void)out_size; (void)ws_size;
  float* hist = (float*)d_ws;
  float* meta = hist + (size_t)FN * HWPIX;
  hipMemsetAsync(d_ws, 0, (size_t)FN * HWPIX * sizeof(float), stream);
  setup_kernel<<<1, 64, 0, stream>>>(d_in[0], d_in[1], d_in[2], d_in[3], meta);
  chaos_kernel<<<NP / 256, 256, 0, stream>>>(meta, hist);
  compose_kernel<<<HWPIX / 256, 256, 0, stream>>>(hist, meta, d_out);
}

// Round 2
// 686.411 us; speedup vs baseline: 1.0709x; 1.0709x over previous
//
#include <hip/hip_runtime.h>
#include <hip/hip_bf16.h>
#include <math.h>

// ============================================================================
// Fractal-flame chaos game — bit-exact reproduction of the JAX reference RNG.
// R1: replicated histograms (R chosen from ws_size, lane-keyed) to break
//     same-address atomic serialization; warm/main loop split + unroll for
//     atomic ILP; float4 replica-reduce fused into compose.
// ============================================================================

#define RNG_PARTITIONABLE 1
#define OUT_BF16 0
#define COLSUM_F32_ACCUM 1

typedef unsigned int u32;
typedef unsigned short u16;

static constexpr int FN = 8;
static constexpr int HH = 1024;
static constexpr int WW = 1024;
static constexpr int NP = 65536;
static constexpr int TI = 48;
static constexpr int WARM = 8;
static constexpr int HWPIX = HH * WW;
static constexpr int MAXR = 8;

// meta layout (float/u32 indices into meta block after hist replicas in ws)
static constexpr int META_CUMPT = 0;    // 64 f32: cumP transposed [cur][next]
static constexpr int META_AFF   = 64;   // 48 f32
static constexpr int META_CT    = 112;  // 24 f32
static constexpr int META_BG    = 136;  // 3 f32
static constexpr int META_FLAG  = 139;  // 1 f32 (1.0 if bf16 inputs)
static constexpr int META_KEYS  = 140;  // 96 u32 (48 key pairs)
static constexpr int META_KX    = 236;  // 2 u32
static constexpr int META_K2S   = 238;  // 2 u32  (contiguous with KX)

struct U2 { u32 x, y; };

// ---------------------------------------------------------------- threefry2x32
__device__ __forceinline__ U2 tf2x32(u32 k0, u32 k1, u32 c0, u32 c1) {
  u32 ks2 = k0 ^ k1 ^ 0x1BD11BDAu;
  u32 x0 = c0 + k0, x1 = c1 + k1;
#define TF_R(r) { x0 += x1; x1 = (x1 << (r)) | (x1 >> (32 - (r))); x1 ^= x0; }
  TF_R(13) TF_R(15) TF_R(26) TF_R(6)
  x0 += k1; x1 += ks2 + 1u;
  TF_R(17) TF_R(29) TF_R(16) TF_R(24)
  x0 += ks2; x1 += k0 + 2u;
  TF_R(13) TF_R(15) TF_R(26) TF_R(6)
  x0 += k0; x1 += k1 + 3u;
  TF_R(17) TF_R(29) TF_R(16) TF_R(24)
  x0 += k1; x1 += ks2 + 4u;
  TF_R(13) TF_R(15) TF_R(26) TF_R(6)
  x0 += ks2; x1 += k0 + 5u;
#undef TF_R
  return {x0, x1};
}

__device__ __forceinline__ u32 rbits(U2 key, u32 i, u32 halfN) {
#if RNG_PARTITIONABLE
  (void)halfN;
  U2 r = tf2x32(key.x, key.y, 0u, i);
  return r.x ^ r.y;
#else
  if (i < halfN) { U2 r = tf2x32(key.x, key.y, i, i + halfN); return r.x; }
  else           { U2 r = tf2x32(key.x, key.y, i - halfN, i); return r.y; }
#endif
}

__device__ __forceinline__ float unitf(u32 b) {  // jax uniform [0,1)
  return __uint_as_float((b >> 9) | 0x3F800000u) - 1.0f;
}

// ---------------------------------------------------------------- bf16 helpers
__device__ __forceinline__ float bf2f(u16 h) { return __uint_as_float(((u32)h) << 16); }
__device__ __forceinline__ float rndbf(float x) {
  u32 u = __float_as_uint(x);
  u32 r = (u + 0x7FFFu + ((u >> 16) & 1u)) & 0xFFFF0000u;
  return __uint_as_float(r);
}
__device__ __forceinline__ float rnd_m(float x, bool bf) { return bf ? rndbf(x) : x; }
__device__ __forceinline__ float ldf(const void* p, int i, bool bf) {
  return bf ? bf2f(((const u16*)p)[i]) : ((const float*)p)[i];
}

__device__ __forceinline__ float exp_cr(float x) { return (float)exp((double)x); }

__device__ __forceinline__ float sigchain(float x, bool bf) {
  float e = rnd_m(exp_cr(-x), bf);
  float d = rnd_m(1.0f + e, bf);
  return rnd_m(1.0f / d, bf);
}

__device__ __forceinline__ void atomAddF(float* p, float v) {
  unsafeAtomicAdd(p, v);  // hardware global_atomic_add_f32
}

// ============================================================== setup kernel
__global__ __launch_bounds__(64) void setup_kernel(const void* pn, const void* affp,
                                                   const void* ctp, const void* bgp,
                                                   float* meta) {
  __shared__ int vote;
  __shared__ float sP[64];
  __shared__ u32 sroot[8];
  int tid = threadIdx.x;
  if (tid == 0) vote = 0;
  __syncthreads();
  {
    float v = fabsf(bf2f(((const u16*)pn)[tid]));
    if (v > 1e-4f && v < 16.0f) atomicAdd(&vote, 1);
  }
  __syncthreads();
  bool bf = (vote >= 50);

  if (tid == 0) {
    meta[META_FLAG] = bf ? 1.0f : 0.0f;
    u32* mu = (u32*)meta;
#if RNG_PARTITIONABLE
    U2 kx = tf2x32(0u, 42u, 0u, 0u);
    U2 ks = tf2x32(0u, 42u, 0u, 1u);
    U2 kl = tf2x32(0u, 42u, 0u, 2u);
    U2 k2 = tf2x32(ks.x, ks.y, 0u, 1u);
#else
    U2 t0 = tf2x32(0u, 42u, 0u, 3u), t1 = tf2x32(0u, 42u, 1u, 4u), t2 = tf2x32(0u, 42u, 2u, 5u);
    U2 kx{t0.x, t1.x}, ks{t2.x, t0.y}, kl{t1.y, t2.y};
    U2 r0 = tf2x32(ks.x, ks.y, 0u, 2u), r1 = tf2x32(ks.x, ks.y, 1u, 3u);
    U2 k2{r0.y, r1.y};
#endif
    sroot[0] = kx.x; sroot[1] = kx.y; sroot[2] = ks.x; sroot[3] = ks.y;
    sroot[4] = kl.x; sroot[5] = kl.y; sroot[6] = k2.x; sroot[7] = k2.y;
    mu[META_KX] = kx.x; mu[META_KX + 1] = kx.y;
    mu[META_K2S] = k2.x; mu[META_K2S + 1] = k2.y;
  }

  float c001 = bf ? 0.00099945068359375f : 0.001f;
  sP[tid] = rnd_m(sigchain(ldf(pn, tid, bf), bf) + c001, bf);
  if (tid < 48) meta[META_AFF + tid] = ldf(affp, tid, bf);
  if (tid < 24) meta[META_CT + tid] = sigchain(ldf(ctp, tid, bf), bf);
  if (tid < 3)  meta[META_BG + tid] = sigchain(ldf(bgp, tid, bf), bf);
  __syncthreads();

  if (tid < 48) {
    U2 kl{sroot[4], sroot[5]};
    u32* mu = (u32*)meta;
#if RNG_PARTITIONABLE
    U2 kt = tf2x32(kl.x, kl.y, 0u, (u32)tid);
#else
    u32 e0 = 2u * tid, e1 = 2u * tid + 1u;
    u32 w0 = (e0 < 48u) ? tf2x32(kl.x, kl.y, e0, e0 + 48u).x : tf2x32(kl.x, kl.y, e0 - 48u, e0).y;
    u32 w1 = (e1 < 48u) ? tf2x32(kl.x, kl.y, e1, e1 + 48u).x : tf2x32(kl.x, kl.y, e1 - 48u, e1).y;
    U2 kt{w0, w1};
#endif
    mu[META_KEYS + 2 * tid]     = kt.x;
    mu[META_KEYS + 2 * tid + 1] = kt.y;
  }

  if (tid < 8) {
    int c = tid;
    float a[8];
#if COLSUM_F32_ACCUM
    float cs = 0.0f;
    for (int r = 0; r < 8; ++r) cs += sP[r * 8 + c];
    cs = rnd_m(cs, bf);
#else
    float cs = 0.0f;
    for (int r = 0; r < 8; ++r) cs = rnd_m(cs + sP[r * 8 + c], bf);
#endif
    for (int r = 0; r < 8; ++r) a[r] = rnd_m(sP[r * 8 + c] / cs, bf);
    float b0 = rnd_m(a[0] + a[1], bf), b1 = rnd_m(a[2] + a[3], bf);
    float b2 = rnd_m(a[4] + a[5], bf), b3 = rnd_m(a[6] + a[7], bf);
    float c0 = rnd_m(b0 + b1, bf), c1v = rnd_m(b2 + b3, bf);
    float d0 = rnd_m(c0 + c1v, bf);
    float s5 = rnd_m(c0 + b2, bf);
    float cum[8] = { a[0], b0, rnd_m(b0 + a[2], bf), c0,
                     rnd_m(c0 + a[4], bf), s5, rnd_m(s5 + a[6], bf), d0 };
    for (int r = 0; r < 8; ++r) meta[META_CUMPT + c * 8 + r] = cum[r];
  }
}

// ============================================================== chaos kernel
__global__ __launch_bounds__(256) void chaos_kernel(const float* __restrict__ meta,
                                                    float* __restrict__ hist, int R) {
  __shared__ float cumPT[64];
  __shared__ float aff[48];
  __shared__ u32 keyw[96];
  __shared__ u32 rk[4];
  int tid = threadIdx.x;
  if (tid < 64) cumPT[tid] = meta[META_CUMPT + tid];
  if (tid < 48) aff[tid] = meta[META_AFF + tid];
  const u32* mu = (const u32*)meta;
  if (tid < 96) keyw[tid] = mu[META_KEYS + tid];
  if (tid < 4)  rk[tid] = mu[META_KX + tid];
  __syncthreads();

  u32 n = blockIdx.x * 256u + (u32)tid;
  U2 kx{rk[0], rk[1]}, k2{rk[2], rk[3]};
  float x = fmaxf(-1.0f, unitf(rbits(kx, 2u * n,      65536u)) * 2.0f - 1.0f);
  float y = fmaxf(-1.0f, unitf(rbits(kx, 2u * n + 1u, 65536u)) * 2.0f - 1.0f);
  int s = (int)(rbits(k2, n, 32768u) & 7u);

  // lane-keyed replica: same-pixel collisions within and across waves are
  // spread over R distinct addresses.
  float* hrep = hist + (size_t)(tid % R) * (FN * (size_t)HWPIX);

  // ---- warmup: state update only, no splats --------------------------------
  for (int t = 0; t < WARM; ++t) {
    U2 kt{keyw[2 * t], keyw[2 * t + 1]};
    float u = unitf(rbits(kt, n, 32768u));
    int cnt = 0;
#pragma unroll
    for (int r = 0; r < 8; ++r) cnt += (cumPT[s * 8 + r] < u) ? 1 : 0;
    int nxt = cnt < 7 ? cnt : 7;
    const float* A = &aff[nxt * 6];
    float xn = A[0] * x + A[1] * y + A[2];
    float yn = A[3] * x + A[4] * y + A[5];
    x = xn; y = yn; s = nxt;
  }

  // ---- main: unrolled so >=8 atomics are in flight (distinct regs) ---------
#pragma unroll 2
  for (int t = WARM; t < TI; ++t) {
    U2 kt{keyw[2 * t], keyw[2 * t + 1]};
    float u = unitf(rbits(kt, n, 32768u));
    int cnt = 0;
#pragma unroll
    for (int r = 0; r < 8; ++r) cnt += (cumPT[s * 8 + r] < u) ? 1 : 0;
    int nxt = cnt < 7 ? cnt : 7;
    const float* A = &aff[nxt * 6];
    float xn = A[0] * x + A[1] * y + A[2];
    float yn = A[3] * x + A[4] * y + A[5];
    x = xn; y = yn; s = nxt;

    float gx = (x + 1.0f) * 0.5f * 1024.0f - 0.5f;
    float gy = (y + 1.0f) * 0.5f * 1024.0f - 0.5f;
    float fx0 = floorf(gx), fy0 = floorf(gy);
    float fx = gx - fx0, fy = gy - fy0;
    int xi = (int)fx0, yi = (int)fy0;
    float ofx = 1.0f - fx, ofy = 1.0f - fy;
    float* hb = hrep + (size_t)nxt * HWPIX;
    bool vx0 = (u32)xi < 1024u, vx1 = (u32)(xi + 1) < 1024u;
    bool vy0 = (u32)yi < 1024u, vy1 = (u32)(yi + 1) < 1024u;
    if (vx0 && vy0) atomAddF(hb + yi * 1024 + xi,             ofx * ofy);
    if (vx1 && vy0) atomAddF(hb + yi * 1024 + (xi + 1),       fx * ofy);
    if (vx0 && vy1) atomAddF(hb + (yi + 1) * 1024 + xi,       ofx * fy);
    if (vx1 && vy1) atomAddF(hb + (yi + 1) * 1024 + (xi + 1), fx * fy);
  }
}

// ============================================================ compose kernel
// One thread = 4 consecutive pixels (float4 path). Reduces R replicas.
__global__ __launch_bounds__(256) void compose_kernel(const float* __restrict__ hist,
                                                      const float* __restrict__ meta,
                                                      void* __restrict__ outv, int R) {
  int q = blockIdx.x * 256 + threadIdx.x;  // quad index
  if (q >= HWPIX / 4) return;
  bool bf = meta[META_FLAG] != 0.0f;
  const float4* h4 = (const float4*)hist;

  float4 h[8];
#pragma unroll
  for (int f = 0; f < 8; ++f) h[f] = make_float4(0.f, 0.f, 0.f, 0.f);
  for (int r = 0; r < R; ++r) {
    size_t rbase = (size_t)r * (FN * (size_t)(HWPIX / 4));
#pragma unroll
    for (int f = 0; f < 8; ++f) {
      float4 v = h4[rbase + (size_t)f * (HWPIX / 4) + q];
      h[f].x += v.x; h[f].y += v.y; h[f].z += v.z; h[f].w += v.w;
    }
  }

  float nexp = bf ? 0.10009765625f : 0.1f;
  float ct[24], bg[3];
#pragma unroll
  for (int i = 0; i < 24; ++i) ct[i] = meta[META_CT + i];
#pragma unroll
  for (int c = 0; c < 3; ++c) bg[c] = meta[META_BG + c];

  float4 o[3];
  const float* hf = (const float*)h;
#pragma unroll
  for (int j = 0; j < 4; ++j) {
    float hs = 0.f;
#pragma unroll
    for (int f = 0; f < 8; ++f) hs += hf[f * 4 + j];
    float denom = hs + 1e-5f;
    float inten = log1pf(hs * nexp);
    float alpha = fminf(fmaxf(inten, 0.0f), 1.0f);
    float oma = 1.0f - alpha;
#pragma unroll
    for (int c = 0; c < 3; ++c) {
      float rgb = 0.0f;
#pragma unroll
      for (int f = 0; f < 8; ++f) rgb += ct[c * 8 + f] * (hf[f * 4 + j] / denom);
      float v = fmaxf(rgb * alpha, 1e-8f);
      float val = sqrtf(v) + bg[c] * oma;
      ((float*)&o[c])[j] = val;
    }
  }
#if OUT_BF16
#pragma unroll
  for (int c = 0; c < 3; ++c)
    for (int j = 0; j < 4; ++j)
      ((__hip_bfloat16*)outv)[c * HWPIX + q * 4 + j] = __float2bfloat16(((float*)&o[c])[j]);
#else
  float4* out4 = (float4*)outv;
#pragma unroll
  for (int c = 0; c < 3; ++c) out4[(size_t)c * (HWPIX / 4) + q] = o[c];
#endif
}

// ================================================================= launcher
extern "C" void kernel_launch(void* const* d_in, const int* in_sizes, int n_in,
                              void* d_out, int out_size, void* d_ws, size_t ws_size,
                              hipStream_t stream) {
  (void)in_sizes; (void)n_in; (void)out_size;
  size_t histElems = (size_t)FN * HWPIX;           // one replica, f32 elems
  size_t availElems = ws_size / sizeof(float);
  int R = 1;
  if (availElems > histElems + 4096) {
    size_t r = (availElems - 4096) / histElems;
    R = (int)(r < (size_t)MAXR ? r : (size_t)MAXR);
    if (R < 1) R = 1;
  }
  float* hist = (float*)d_ws;
  float* meta = hist + (size_t)R * histElems;
  hipMemsetAsync(d_ws, 0, (size_t)R * histElems * sizeof(float), stream);
  setup_kernel<<<1, 64, 0, stream>>>(d_in[0], d_in[1], d_in[2], d_in[3], meta);
  chaos_kernel<<<NP / 256, 256, 0, stream>>>(meta, hist, R);
  compose_kernel<<<(HWPIX / 4 + 255) / 256, 256, 0, stream>>>(hist, meta, d_out, R);
}

// Round 5
// 680.398 us; speedup vs baseline: 1.0803x; 1.0088x over previous
//
#include <hip/hip_runtime.h>
#include <hip/hip_bf16.h>
#include <math.h>

// ============================================================================
// Fractal-flame chaos game — bit-exact reproduction of the JAX reference RNG.
// R2 (resubmit x2 after infra timeouts): atomic MLP. Per-batch(8) precomputed
// threefry (u_t independent of state), fully-unrolled state+splat region =>
// ~32 atomics in flight per wave. Per-replica XOR swizzle so replicated hot
// pixels hit distinct channels.
// ============================================================================

#define RNG_PARTITIONABLE 1
#define OUT_BF16 0
#define COLSUM_F32_ACCUM 1

typedef unsigned int u32;
typedef unsigned short u16;

static constexpr int FN = 8;
static constexpr int HH = 1024;
static constexpr int WW = 1024;
static constexpr int NP = 65536;
static constexpr int TI = 48;
static constexpr int WARM = 8;
static constexpr int HWPIX = HH * WW;
static constexpr int MAXR = 8;

static constexpr int META_CUMPT = 0;    // 64 f32: cumP transposed [cur][next]
static constexpr int META_AFF   = 64;   // 48 f32
static constexpr int META_CT    = 112;  // 24 f32
static constexpr int META_BG    = 136;  // 3 f32
static constexpr int META_FLAG  = 139;  // 1 f32
static constexpr int META_KEYS  = 140;  // 96 u32 (48 key pairs)
static constexpr int META_KX    = 236;  // 2 u32
static constexpr int META_K2S   = 238;  // 2 u32

struct U2 { u32 x, y; };

__device__ __forceinline__ u32 swz_of(int r) {
  // per-replica pixel-index XOR; multiple of 4 (keeps float4 quads intact)
  return (u32)(((r * 2654435761u) >> 10) & (u32)(HWPIX - 1) & ~3u);
}

// ---------------------------------------------------------------- threefry2x32
__device__ __forceinline__ U2 tf2x32(u32 k0, u32 k1, u32 c0, u32 c1) {
  u32 ks2 = k0 ^ k1 ^ 0x1BD11BDAu;
  u32 x0 = c0 + k0, x1 = c1 + k1;
#define TF_R(r) { x0 += x1; x1 = (x1 << (r)) | (x1 >> (32 - (r))); x1 ^= x0; }
  TF_R(13) TF_R(15) TF_R(26) TF_R(6)
  x0 += k1; x1 += ks2 + 1u;
  TF_R(17) TF_R(29) TF_R(16) TF_R(24)
  x0 += ks2; x1 += k0 + 2u;
  TF_R(13) TF_R(15) TF_R(26) TF_R(6)
  x0 += k0; x1 += k1 + 3u;
  TF_R(17) TF_R(29) TF_R(16) TF_R(24)
  x0 += k1; x1 += ks2 + 4u;
  TF_R(13) TF_R(15) TF_R(26) TF_R(6)
  x0 += ks2; x1 += k0 + 5u;
#undef TF_R
  return {x0, x1};
}

__device__ __forceinline__ u32 rbits(U2 key, u32 i, u32 halfN) {
#if RNG_PARTITIONABLE
  (void)halfN;
  U2 r = tf2x32(key.x, key.y, 0u, i);
  return r.x ^ r.y;
#else
  if (i < halfN) { U2 r = tf2x32(key.x, key.y, i, i + halfN); return r.x; }
  else           { U2 r = tf2x32(key.x, key.y, i - halfN, i); return r.y; }
#endif
}

__device__ __forceinline__ float unitf(u32 b) {  // jax uniform [0,1)
  return __uint_as_float((b >> 9) | 0x3F800000u) - 1.0f;
}

// ---------------------------------------------------------------- bf16 helpers
__device__ __forceinline__ float bf2f(u16 h) { return __uint_as_float(((u32)h) << 16); }
__device__ __forceinline__ float rndbf(float x) {
  u32 u = __float_as_uint(x);
  u32 r = (u + 0x7FFFu + ((u >> 16) & 1u)) & 0xFFFF0000u;
  return __uint_as_float(r);
}
__device__ __forceinline__ float rnd_m(float x, bool bf) { return bf ? rndbf(x) : x; }
__device__ __forceinline__ float ldf(const void* p, int i, bool bf) {
  return bf ? bf2f(((const u16*)p)[i]) : ((const float*)p)[i];
}

__device__ __forceinline__ float exp_cr(float x) { return (float)exp((double)x); }

__device__ __forceinline__ float sigchain(float x, bool bf) {
  float e = rnd_m(exp_cr(-x), bf);
  float d = rnd_m(1.0f + e, bf);
  return rnd_m(1.0f / d, bf);
}

__device__ __forceinline__ void atomAddF(float* p, float v) {
  unsafeAtomicAdd(p, v);  // global_atomic_add_f32, no return
}

// ============================================================== setup kernel
__global__ __launch_bounds__(64) void setup_kernel(const void* pn, const void* affp,
                                                   const void* ctp, const void* bgp,
                                                   float* meta) {
  __shared__ int vote;
  __shared__ float sP[64];
  __shared__ u32 sroot[8];
  int tid = threadIdx.x;
  if (tid == 0) vote = 0;
  __syncthreads();
  {
    float v = fabsf(bf2f(((const u16*)pn)[tid]));
    if (v > 1e-4f && v < 16.0f) atomicAdd(&vote, 1);
  }
  __syncthreads();
  bool bf = (vote >= 50);

  if (tid == 0) {
    meta[META_FLAG] = bf ? 1.0f : 0.0f;
    u32* mu = (u32*)meta;
#if RNG_PARTITIONABLE
    U2 kx = tf2x32(0u, 42u, 0u, 0u);
    U2 ks = tf2x32(0u, 42u, 0u, 1u);
    U2 kl = tf2x32(0u, 42u, 0u, 2u);
    U2 k2 = tf2x32(ks.x, ks.y, 0u, 1u);
#else
    U2 t0 = tf2x32(0u, 42u, 0u, 3u), t1 = tf2x32(0u, 42u, 1u, 4u), t2 = tf2x32(0u, 42u, 2u, 5u);
    U2 kx{t0.x, t1.x}, ks{t2.x, t0.y}, kl{t1.y, t2.y};
    U2 r0 = tf2x32(ks.x, ks.y, 0u, 2u), r1 = tf2x32(ks.x, ks.y, 1u, 3u);
    U2 k2{r0.y, r1.y};
#endif
    sroot[0] = kx.x; sroot[1] = kx.y; sroot[2] = ks.x; sroot[3] = ks.y;
    sroot[4] = kl.x; sroot[5] = kl.y; sroot[6] = k2.x; sroot[7] = k2.y;
    mu[META_KX] = kx.x; mu[META_KX + 1] = kx.y;
    mu[META_K2S] = k2.x; mu[META_K2S + 1] = k2.y;
  }

  float c001 = bf ? 0.00099945068359375f : 0.001f;
  sP[tid] = rnd_m(sigchain(ldf(pn, tid, bf), bf) + c001, bf);
  if (tid < 48) meta[META_AFF + tid] = ldf(affp, tid, bf);
  if (tid < 24) meta[META_CT + tid] = sigchain(ldf(ctp, tid, bf), bf);
  if (tid < 3)  meta[META_BG + tid] = sigchain(ldf(bgp, tid, bf), bf);
  __syncthreads();

  if (tid < 48) {
    U2 kl{sroot[4], sroot[5]};
    u32* mu = (u32*)meta;
#if RNG_PARTITIONABLE
    U2 kt = tf2x32(kl.x, kl.y, 0u, (u32)tid);
#else
    u32 e0 = 2u * tid, e1 = 2u * tid + 1u;
    u32 w0 = (e0 < 48u) ? tf2x32(kl.x, kl.y, e0, e0 + 48u).x : tf2x32(kl.x, kl.y, e0 - 48u, e0).y;
    u32 w1 = (e1 < 48u) ? tf2x32(kl.x, kl.y, e1, e1 + 48u).x : tf2x32(kl.x, kl.y, e1 - 48u, e1).y;
    U2 kt{w0, w1};
#endif
    mu[META_KEYS + 2 * tid]     = kt.x;
    mu[META_KEYS + 2 * tid + 1] = kt.y;
  }

  if (tid < 8) {
    int c = tid;
    float a[8];
#if COLSUM_F32_ACCUM
    float cs = 0.0f;
    for (int r = 0; r < 8; ++r) cs += sP[r * 8 + c];
    cs = rnd_m(cs, bf);
#else
    float cs = 0.0f;
    for (int r = 0; r < 8; ++r) cs = rnd_m(cs + sP[r * 8 + c], bf);
#endif
    for (int r = 0; r < 8; ++r) a[r] = rnd_m(sP[r * 8 + c] / cs, bf);
    float b0 = rnd_m(a[0] + a[1], bf), b1 = rnd_m(a[2] + a[3], bf);
    float b2 = rnd_m(a[4] + a[5], bf), b3 = rnd_m(a[6] + a[7], bf);
    float c0 = rnd_m(b0 + b1, bf), c1v = rnd_m(b2 + b3, bf);
    float d0 = rnd_m(c0 + c1v, bf);
    float s5 = rnd_m(c0 + b2, bf);
    float cum[8] = { a[0], b0, rnd_m(b0 + a[2], bf), c0,
                     rnd_m(c0 + a[4], bf), s5, rnd_m(s5 + a[6], bf), d0 };
    for (int r = 0; r < 8; ++r) meta[META_CUMPT + c * 8 + r] = cum[r];
  }
}

// ============================================================== chaos kernel
__global__ __launch_bounds__(256) void chaos_kernel(const float* __restrict__ meta,
                                                    float* __restrict__ hist, int R) {
  __shared__ float cumPT[64];
  __shared__ float aff8[64];   // 8 rows x 8 (padded from 6) for float4 reads
  __shared__ u32 keyw[96];
  __shared__ u32 rk[4];
  int tid = threadIdx.x;
  if (tid < 64) cumPT[tid] = meta[META_CUMPT + tid];
  if (tid < 48) aff8[(tid / 6) * 8 + (tid % 6)] = meta[META_AFF + tid];
  const u32* mu = (const u32*)meta;
  if (tid < 96) keyw[tid] = mu[META_KEYS + tid];
  if (tid < 4)  rk[tid] = mu[META_KX + tid];
  __syncthreads();

  u32 n = blockIdx.x * 256u + (u32)tid;
  U2 kx{rk[0], rk[1]}, k2{rk[2], rk[3]};
  float x = fmaxf(-1.0f, unitf(rbits(kx, 2u * n,      65536u)) * 2.0f - 1.0f);
  float y = fmaxf(-1.0f, unitf(rbits(kx, 2u * n + 1u, 65536u)) * 2.0f - 1.0f);
  int s = (int)(rbits(k2, n, 32768u) & 7u);

  int rr = tid & (R - 1);              // R forced to power of two by launcher
  float* hrep = hist + (size_t)rr * (FN * (size_t)HWPIX);
  u32 swzr = swz_of(rr);

  float uv[8];

  // ---- batch 0: warmup (state only) ----------------------------------------
#pragma unroll
  for (int j = 0; j < 8; ++j) {
    U2 kt{keyw[2 * j], keyw[2 * j + 1]};
    uv[j] = unitf(rbits(kt, n, 32768u));
  }
#pragma unroll
  for (int j = 0; j < 8; ++j) {
    float u = uv[j];
    float4 c0 = *(const float4*)&cumPT[s * 8];
    float4 c1 = *(const float4*)&cumPT[s * 8 + 4];
    int cnt = (c0.x < u) + (c0.y < u) + (c0.z < u) + (c0.w < u)
            + (c1.x < u) + (c1.y < u) + (c1.z < u) + (c1.w < u);
    int nxt = cnt < 7 ? cnt : 7;
    float4 A0 = *(const float4*)&aff8[nxt * 8];
    float4 A1 = *(const float4*)&aff8[nxt * 8 + 4];
    float xn = A0.x * x + A0.y * y + A0.z;
    float yn = A0.w * x + A1.x * y + A1.y;
    x = xn; y = yn; s = nxt;
  }

  // ---- batches 1..5: 8 threefry (ILP) then 8 state+splat (32 atomics) ------
  for (int b = 1; b < 6; ++b) {
#pragma unroll
    for (int j = 0; j < 8; ++j) {
      U2 kt{keyw[16 * b + 2 * j], keyw[16 * b + 2 * j + 1]};
      uv[j] = unitf(rbits(kt, n, 32768u));
    }
#pragma unroll
    for (int j = 0; j < 8; ++j) {
      float u = uv[j];
      float4 c0 = *(const float4*)&cumPT[s * 8];
      float4 c1 = *(const float4*)&cumPT[s * 8 + 4];
      int cnt = (c0.x < u) + (c0.y < u) + (c0.z < u) + (c0.w < u)
              + (c1.x < u) + (c1.y < u) + (c1.z < u) + (c1.w < u);
      int nxt = cnt < 7 ? cnt : 7;
      float4 A0 = *(const float4*)&aff8[nxt * 8];
      float4 A1 = *(const float4*)&aff8[nxt * 8 + 4];
      float xn = A0.x * x + A0.y * y + A0.z;
      float yn = A0.w * x + A1.x * y + A1.y;
      x = xn; y = yn; s = nxt;

      float gx = (x + 1.0f) * 0.5f * 1024.0f - 0.5f;
      float gy = (y + 1.0f) * 0.5f * 1024.0f - 0.5f;
      float fx0 = floorf(gx), fy0 = floorf(gy);
      float fx = gx - fx0, fy = gy - fy0;
      int xi = (int)fx0, yi = (int)fy0;
      float ofx = 1.0f - fx, ofy = 1.0f - fy;
      float* hb = hrep + (size_t)nxt * HWPIX;
      bool vx0 = (u32)xi < 1024u, vx1 = (u32)(xi + 1) < 1024u;
      bool vy0 = (u32)yi < 1024u, vy1 = (u32)(yi + 1) < 1024u;
      int p00 = yi * 1024 + xi;
      if (vx0 && vy0) atomAddF(hb + ((u32)p00 ^ swzr),          ofx * ofy);
      if (vx1 && vy0) atomAddF(hb + ((u32)(p00 + 1) ^ swzr),    fx * ofy);
      if (vx0 && vy1) atomAddF(hb + ((u32)(p00 + 1024) ^ swzr), ofx * fy);
      if (vx1 && vy1) atomAddF(hb + ((u32)(p00 + 1025) ^ swzr), fx * fy);
    }
  }
}

// ============================================================ compose kernel
__global__ __launch_bounds__(256) void compose_kernel(const float* __restrict__ hist,
                                                      const float* __restrict__ meta,
                                                      void* __restrict__ outv, int R) {
  int q = blockIdx.x * 256 + threadIdx.x;  // quad index
  if (q >= HWPIX / 4) return;
  bool bf = meta[META_FLAG] != 0.0f;
  const float4* h4 = (const float4*)hist;

  float4 h[8];
#pragma unroll
  for (int f = 0; f < 8; ++f) h[f] = make_float4(0.f, 0.f, 0.f, 0.f);
  for (int r = 0; r < R; ++r) {
    size_t rbase = (size_t)r * (FN * (size_t)(HWPIX / 4));
    u32 qs = (u32)q ^ (swz_of(r) >> 2);
#pragma unroll
    for (int f = 0; f < 8; ++f) {
      float4 v = h4[rbase + (size_t)f * (HWPIX / 4) + qs];
      h[f].x += v.x; h[f].y += v.y; h[f].z += v.z; h[f].w += v.w;
    }
  }

  float nexp = bf ? 0.10009765625f : 0.1f;
  float ct[24], bg[3];
#pragma unroll
  for (int i = 0; i < 24; ++i) ct[i] = meta[META_CT + i];
#pragma unroll
  for (int c = 0; c < 3; ++c) bg[c] = meta[META_BG + c];

  float4 o[3];
  const float* hf = (const float*)h;
#pragma unroll
  for (int j = 0; j < 4; ++j) {
    float hs = 0.f;
#pragma unroll
    for (int f = 0; f < 8; ++f) hs += hf[f * 4 + j];
    float denom = hs + 1e-5f;
    float inten = log1pf(hs * nexp);
    float alpha = fminf(fmaxf(inten, 0.0f), 1.0f);
    float oma = 1.0f - alpha;
#pragma unroll
    for (int c = 0; c < 3; ++c) {
      float rgb = 0.0f;
#pragma unroll
      for (int f = 0; f < 8; ++f) rgb += ct[c * 8 + f] * (hf[f * 4 + j] / denom);
      float v = fmaxf(rgb * alpha, 1e-8f);
      float val = sqrtf(v) + bg[c] * oma;
      ((float*)&o[c])[j] = val;
    }
  }
#if OUT_BF16
#pragma unroll
  for (int c = 0; c < 3; ++c)
    for (int j = 0; j < 4; ++j)
      ((__hip_bfloat16*)outv)[c * HWPIX + q * 4 + j] = __float2bfloat16(((float*)&o[c])[j]);
#else
  float4* out4 = (float4*)outv;
#pragma unroll
  for (int c = 0; c < 3; ++c) out4[(size_t)c * (HWPIX / 4) + q] = o[c];
#endif
}

// ================================================================= launcher
extern "C" void kernel_launch(void* const* d_in, const int* in_sizes, int n_in,
                              void* d_out, int out_size, void* d_ws, size_t ws_size,
                              hipStream_t stream) {
  (void)in_sizes; (void)n_in; (void)out_size;
  size_t histElems = (size_t)FN * HWPIX;
  size_t availElems = ws_size / sizeof(float);
  int R = 1;
  if (availElems > histElems + 4096) {
    size_t r = (availElems - 4096) / histElems;
    if (r > (size_t)MAXR) r = MAXR;
    while ((size_t)(R << 1) <= r) R <<= 1;   // force power of two
  }
  float* hist = (float*)d_ws;
  float* meta = hist + (size_t)R * histElems;
  hipMemsetAsync(d_ws, 0, (size_t)R * histElems * sizeof(float), stream);
  setup_kernel<<<1, 64, 0, stream>>>(d_in[0], d_in[1], d_in[2], d_in[3], meta);
  chaos_kernel<<<NP / 256, 256, 0, stream>>>(meta, hist, R);
  compose_kernel<<<(HWPIX / 4 + 255) / 256, 256, 0, stream>>>(hist, meta, d_out, R);
}